// Round 1
// baseline (475.059 us; speedup 1.0000x reference)
//
#include <hip/hip_runtime.h>

// SNN forward, thread-per-sample restructure.
//
// Old kernel was LDS-pipe-bound: 32-lane broadcast reads of x delivered 32B
// unique data per 1KB LDS access; per-CU LDS cycles ~= whole runtime.
//
// New structure: each thread owns one sample.
//  - x quads (4 timesteps x 28 rows) live in 112 VGPRs, loaded straight from
//    global (no LDS for x). Chunk c+1 loads issue before chunk c's layer-2
//    phase to hide latency.
//  - W1 rows are wave-uniform -> scalar (SGPR) loads, ping-pong pipelined.
//    v_fmac with SGPR weight + VGPR x: every FMA does 64 useful MACs.
//  - Spike masks built in-register as sum of spf*2^(o&15)  (exact <= 65535),
//    no __ballot, no lane divergence anywhere.
//  - Layer-2: same nibble tables, read as float2 per thread (16 nibble values
//    map to 16 distinct banks -> conflict-free); k-ascending fold preserved
//    bit-exactly.
//  - v1[32] per-thread state lives in LDS (runtime-indexed arrays must not be
//    VGPR arrays), 1 read + 1 write per (o, chunk): trivial traffic.
//
// Numerics are kept identical to the previous passing kernel (absmax 0.0):
// sequential-i fmaf chain, v1 += acc + b1o, nibble fold order, cnt / 28.0f.

#define THREADS 128

__global__ __launch_bounds__(THREADS, 1) void snn_if_kernel(
    const float* __restrict__ x,    // [B][28][28]  (b, i, t), t fastest
    const float* __restrict__ W1,   // [32][28]
    const float* __restrict__ b1,   // [32]
    const float* __restrict__ W2,   // [10][32]
    const float* __restrict__ b2,   // [10]
    float* __restrict__ out,        // [B][10]
    int B)
{
    __shared__ float Tbl[1280];             // [k<8][nib<16][o2<10]
    __shared__ float v1L[32 * THREADS];     // layer-1 membrane state [o][tid]

    const int tid = threadIdx.x;
    const int s   = blockIdx.x * THREADS + tid;

    // ---- build layer-2 nibble tables (identical arithmetic to prev kernel)
    for (int e = tid; e < 1280; e += THREADS) {
        int o2 = e % 10;
        int tn = e / 10;         // 0..127
        int n  = tn & 15;
        int k  = tn >> 4;
        float v = 0.f;
        if (n & 1) v += W2[o2 * 32 + 4 * k + 0];
        if (n & 2) v += W2[o2 * 32 + 4 * k + 1];
        if (n & 4) v += W2[o2 * 32 + 4 * k + 2];
        if (n & 8) v += W2[o2 * 32 + 4 * k + 3];
        Tbl[e] = v;
    }
    __syncthreads();

    if (s >= B) return;   // after the only barrier; safe

    const float* xs = x + (size_t)s * 784;

    // init per-thread v1 state in LDS (bank = tid -> conflict-free)
    #pragma unroll
    for (int o = 0; o < 32; ++o) v1L[o * THREADS + tid] = 0.f;

    float v2[10], cnt[10], b2v[10];
    #pragma unroll
    for (int j = 0; j < 10; ++j) { v2[j] = 0.f; cnt[j] = 0.f; b2v[j] = b2[j]; }

    // x quads for current 4-t chunk: xq[i] = x[s][i][t0..t0+3]
    float4 xq[28];
    #pragma unroll
    for (int i = 0; i < 28; ++i)
        xq[i] = *reinterpret_cast<const float4*>(xs + i * 28);   // t0 = 0

    // W1 row ping-pong buffers (uniform addresses -> SGPRs)
    float wA[28], wB[28];
    #pragma unroll
    for (int i = 0; i < 28; ++i) wA[i] = W1[i];                  // row 0

    #pragma unroll 1
    for (int t0 = 0; t0 < 28; t0 += 4) {
        float mlo[4] = {0.f, 0.f, 0.f, 0.f};   // spike masks (bits 0..15) as exact f32
        float mhi[4] = {0.f, 0.f, 0.f, 0.f};   // bits 16..31

        // ---- one layer-1 neuron: dot(28) for 4 timesteps + IF dynamics ----
        auto do_o = [&](int o, const float (&w)[28]) {
            float a0 = 0.f, a1 = 0.f, a2 = 0.f, a3 = 0.f;
            #pragma unroll
            for (int i = 0; i < 28; ++i) {     // strict sequential-i fmaf chain
                const float wi = w[i];
                a0 = fmaf(wi, xq[i].x, a0);
                a1 = fmaf(wi, xq[i].y, a1);
                a2 = fmaf(wi, xq[i].z, a2);
                a3 = fmaf(wi, xq[i].w, a3);
            }
            const float b1o = b1[o];                       // uniform -> SGPR
            const float pw  = (float)(1u << (o & 15));     // uniform
            float v1r = v1L[o * THREADS + tid];
            const float av[4] = {a0, a1, a2, a3};
            #pragma unroll
            for (int tt = 0; tt < 4; ++tt) {               // t-sequential IF
                v1r = v1r + (av[tt] + b1o);                // v += h1
                const bool sp = (v1r >= 1.0f);
                const float spf = sp ? pw : 0.f;
                if (o < 16) mlo[tt] += spf; else mhi[tt] += spf;  // uniform branch
                v1r = sp ? 0.0f : v1r;                     // hard reset
            }
            v1L[o * THREADS + tid] = v1r;
        };

        #pragma unroll 1
        for (int ob = 0; ob < 16; ++ob) {
            const int o0 = 2 * ob, o1 = 2 * ob + 1;
            #pragma unroll
            for (int i = 0; i < 28; ++i) wB[i] = W1[o1 * 28 + i];
            do_o(o0, wA);
            const int onext = (o1 + 1) & 31;   // wraps to row 0 -> primed for next chunk
            #pragma unroll
            for (int i = 0; i < 28; ++i) wA[i] = W1[onext * 28 + i];
            do_o(o1, wB);
        }

        // ---- prefetch next chunk's x quads; latency hides under layer-2 ----
        if (t0 + 4 < 28) {
            #pragma unroll
            for (int i = 0; i < 28; ++i)
                xq[i] = *reinterpret_cast<const float4*>(xs + i * 28 + t0 + 4);
        }

        // ---- layer 2 + IF for the 4 timesteps (exact nibble-fold order) ----
        #pragma unroll
        for (int tt = 0; tt < 4; ++tt) {
            const unsigned mask = (unsigned)mlo[tt] | ((unsigned)mhi[tt] << 16);
            float acc2[10];
            #pragma unroll
            for (int j = 0; j < 10; ++j) acc2[j] = 0.f;
            #pragma unroll
            for (int k = 0; k < 8; ++k) {                  // k ascending (exact match)
                const unsigned nib = (mask >> (4 * k)) & 15u;
                const float2* p =
                    reinterpret_cast<const float2*>(&Tbl[k * 160 + nib * 10]);
                #pragma unroll
                for (int j = 0; j < 5; ++j) {              // ds_read_b64, 8B-aligned
                    const float2 v = p[j];
                    acc2[2 * j]     += v.x;
                    acc2[2 * j + 1] += v.y;
                }
            }
            #pragma unroll
            for (int o2 = 0; o2 < 10; ++o2) {
                const float v2n = v2[o2] + (acc2[o2] + b2v[o2]);  // v += h2
                const bool sp2 = (v2n >= 1.0f);
                cnt[o2] += sp2 ? 1.0f : 0.0f;
                v2[o2]   = sp2 ? 0.0f : v2n;
            }
        }
    }

    // ---- firing rates; same division expression as before ----
    #pragma unroll
    for (int j = 0; j < 5; ++j) {
        float2 r;
        r.x = cnt[2 * j]     / 28.0f;
        r.y = cnt[2 * j + 1] / 28.0f;
        *reinterpret_cast<float2*>(out + (size_t)s * 10 + 2 * j) = r;
    }
}

extern "C" void kernel_launch(void* const* d_in, const int* in_sizes, int n_in,
                              void* d_out, int out_size, void* d_ws, size_t ws_size,
                              hipStream_t stream) {
    const float* x  = (const float*)d_in[0];
    const float* W1 = (const float*)d_in[1];
    const float* b1 = (const float*)d_in[2];
    const float* W2 = (const float*)d_in[3];
    const float* b2 = (const float*)d_in[4];
    float* out = (float*)d_out;

    int B = in_sizes[0] / 784;                 // 65536
    int grid = (B + THREADS - 1) / THREADS;    // 512
    snn_if_kernel<<<grid, THREADS, 0, stream>>>(x, W1, b1, W2, b2, out, B);
}

// Round 3
// 361.048 us; speedup vs baseline: 1.3158x; 1.3158x over previous
//
#include <hip/hip_runtime.h>

// SNN forward, block-phase decomposition (r3 = r2 + LDS-layout fixes; r2 bench
// died to an infra flake, never profiled).
//
// r1 failed on memory: per-lane-strided 16B chunk loads -> 64 lines/instr,
// 4x line overfetch (707 MB) + per-CU miss-queue choke (4.2 B/cyc/CU).
// Fix: never hold x resident; stream it once through a lane-dense mapping.
//
// Per block: 16 iterations x 8 samples. Four phases per iteration,
// remapping lanes each phase; only reduced intermediates transit LDS:
//   A lane=(s,t):  x via 28 COALESCED dword loads (lanes t-adjacent, lines
//                  fully consumed); h1[o] = sum_i W1[o][i]*x[i][t] with W1
//                  row forced uniform via readfirstlane -> s_load/K$;
//                  h1 -> LDS transposed [s][t][o], stride 33 (odd) =>
//                  conflict-free writes (banks (lo+o)%32).
//   B lane=(s,o):  read h1[s][t][o] (banks (t+lo)%32, conflict-free),
//                  sequential IF over t, __ballot per t -> spike mask.
//   C lane=(s,t):  layer-2 via nibble tables [k][16][12] in GLOBAL workspace
//                  (L1-hot; rides the idle VMEM pipe, 3 vec loads/nibble);
//                  h2[10] -> LDS stride 11 (odd, conflict-free).
//   D lane=(s,o2): layer-2 IF scan, firing rate to out.
// 3 barriers/iter (D overlaps next A; disjoint LDS ranges, double-fenced).
//
// Numerics bit-identical to the r0 passing kernel: sequential-i fmaf chain,
// v += (h + b), k-ascending nibble fold, cnt / 28.0f.

#define THREADS 256
#define SPI 8                 // samples per iteration
#define NITER 16              // iterations per block
#define SPB (SPI * NITER)     // 128 samples per block

#define H1_TS 33              // h1L [s][t][o]: t-stride (odd -> bank-perfect)
#define H1_SS (32 * H1_TS)    // 1056 floats/sample (t padded 28->32 for clamped lanes)
#define H2_TS 11              // h2L [s][t][o2]: t-stride (odd)
#define H2_SS 309             // 28*11 + 1

__global__ void build_tbl(const float* __restrict__ W2, float* __restrict__ Tbl)
{
    int e = blockIdx.x * blockDim.x + threadIdx.x;   // Tbl[k][nib][12]
    if (e < 1536) {
        int o2 = e % 12;
        int tn = e / 12;      // 0..127
        int n  = tn & 15;
        int k  = tn >> 4;
        float v = 0.f;
        if (o2 < 10) {
            if (n & 1) v += W2[o2 * 32 + 4 * k + 0];
            if (n & 2) v += W2[o2 * 32 + 4 * k + 1];
            if (n & 4) v += W2[o2 * 32 + 4 * k + 2];
            if (n & 8) v += W2[o2 * 32 + 4 * k + 3];
        }
        Tbl[e] = v;
    }
}

__global__ __launch_bounds__(THREADS, 2) void snn_if_kernel(
    const float* __restrict__ x,    // [B][28][28]  (b, i, t), t fastest
    const float* __restrict__ W1,   // [32][28]
    const float* __restrict__ b1,   // [32]
    const float* __restrict__ W2,   // [10][32] (fallback Tbl build only)
    const float* __restrict__ b2,   // [10]
    const float* __restrict__ TblG, // [8][16][12] nibble tables (may be null)
    float* __restrict__ out,        // [B][10]
    int B)
{
    __shared__ __align__(16) float h1L[8 * H1_SS];    // 33.8 KB
    __shared__ __align__(16) float h2L[8 * H2_SS];    // 9.9 KB
    __shared__ unsigned maskL[8 * 33];                // 1.1 KB
    __shared__ __align__(16) float TblL[1536];        // 6 KB (fallback only)

    const int tid = threadIdx.x;
    const int s   = tid >> 5;    // local sample slot 0..7
    const int lo  = tid & 31;    // t (phases A,C) / o (B) / o2 (D)

    const float* tbl;
    if (TblG != nullptr) {
        tbl = TblG;
    } else {
        for (int e = tid; e < 1536; e += THREADS) {
            int o2 = e % 12;
            int tn = e / 12;
            int n  = tn & 15;
            int k  = tn >> 4;
            float v = 0.f;
            if (o2 < 10) {
                if (n & 1) v += W2[o2 * 32 + 4 * k + 0];
                if (n & 2) v += W2[o2 * 32 + 4 * k + 1];
                if (n & 4) v += W2[o2 * 32 + 4 * k + 2];
                if (n & 8) v += W2[o2 * 32 + 4 * k + 3];
            }
            TblL[e] = v;
        }
        tbl = TblL;
        __syncthreads();
    }

    const float b1v = b1[lo];                       // for phase B
    const float b2v = (lo < 10) ? b2[lo] : 0.f;     // for phase D
    const int   S0  = blockIdx.x * SPB;

    #pragma unroll 1
    for (int it = 0; it < NITER; ++it) {
        const int  sg    = S0 + it * SPI + s;
        const bool valid = sg < B;
        const int  sgc   = valid ? sg : (B - 1);

        // ---------------- phase A: lane (s, t) — h1 GEMM ----------------
        {
            const int t = (lo < 28) ? lo : 27;       // clamp idle lanes
            const float* xp = x + (size_t)sgc * 784 + t;
            float xv[28];
            #pragma unroll
            for (int i = 0; i < 28; ++i) xv[i] = xp[i * 28];  // coalesced dwords

            float* hw = &h1L[s * H1_SS + lo * H1_TS];  // row t (pad rows 28..31)
            #pragma unroll 2
            for (int o = 0; o < 32; ++o) {
                // force wave-uniform (SGPR) W1 row address -> scalar loads
                const int oro = __builtin_amdgcn_readfirstlane(o);
                const float* wr = W1 + oro * 28;
                float h = 0.f;
                #pragma unroll
                for (int i = 0; i < 28; ++i) h = fmaf(wr[i], xv[i], h);
                hw[o] = h;                              // bank (lo+o)%32: free
            }
        }
        __syncthreads();

        // ---------------- phase B: lane (s, o) — IF layer 1 -------------
        {
            const float* hp = &h1L[s * H1_SS + lo];     // column o
            float hr[28];
            #pragma unroll
            for (int t = 0; t < 28; ++t) hr[t] = hp[t * H1_TS];  // bank (t+lo)%32

            float v = 0.f;
            unsigned mym = 0u;
            #pragma unroll
            for (int t = 0; t < 28; ++t) {
                v = v + (hr[t] + b1v);                  // v += h1 (exact order)
                const bool sp = (v >= 1.0f);
                const unsigned long long bal = __ballot(sp);
                if (lo == t) mym = (unsigned)(bal >> (tid & 32));
                v = sp ? 0.0f : v;                      // hard reset
            }
            if (lo < 28) maskL[s * 33 + lo] = mym;
        }
        __syncthreads();

        // ---------------- phase C: lane (s, t) — layer-2 matvec ---------
        {
            const unsigned m = maskL[s * 33 + ((lo < 28) ? lo : 27)];
            float a[10];
            #pragma unroll
            for (int j = 0; j < 10; ++j) a[j] = 0.f;
            #pragma unroll
            for (int k = 0; k < 8; ++k) {               // k ascending (exact)
                const unsigned nib = (m >> (4 * k)) & 15u;
                const float* p = tbl + (k * 192 + (int)nib * 12);  // 48B, 16B-aligned
                const float4 f0 = *(const float4*)(p);
                const float4 f1 = *(const float4*)(p + 4);
                const float2 f2 = *(const float2*)(p + 8);
                a[0] += f0.x; a[1] += f0.y; a[2] += f0.z; a[3] += f0.w;
                a[4] += f1.x; a[5] += f1.y; a[6] += f1.z; a[7] += f1.w;
                a[8] += f2.x; a[9] += f2.y;
            }
            if (lo < 28) {
                float* hp = &h2L[s * H2_SS + lo * H2_TS];
                #pragma unroll
                for (int j = 0; j < 10; ++j) hp[j] = a[j];  // banks 11*lo+j: free
            }
        }
        __syncthreads();

        // ---------------- phase D: lane (s, o2) — IF layer 2 + out ------
        if (lo < 10) {
            float v2 = 0.f, cnt = 0.f;
            const float* hp = &h2L[s * H2_SS + lo];
            #pragma unroll
            for (int t = 0; t < 28; ++t) {
                const float h2 = hp[t * H2_TS];
                const float vn = v2 + (h2 + b2v);       // v += h2 (exact order)
                const bool sp = (vn >= 1.0f);
                cnt += sp ? 1.0f : 0.0f;
                v2 = sp ? 0.0f : vn;
            }
            if (valid) out[(size_t)sg * 10 + lo] = cnt / 28.0f;
        }
        // no barrier: next phase A touches only h1L (disjoint from h2L/out);
        // B(it+1)'s maskL write is double-fenced from C(it)'s read.
    }
}

extern "C" void kernel_launch(void* const* d_in, const int* in_sizes, int n_in,
                              void* d_out, int out_size, void* d_ws, size_t ws_size,
                              hipStream_t stream) {
    const float* x  = (const float*)d_in[0];
    const float* W1 = (const float*)d_in[1];
    const float* b1 = (const float*)d_in[2];
    const float* W2 = (const float*)d_in[3];
    const float* b2 = (const float*)d_in[4];
    float* out = (float*)d_out;

    int B = in_sizes[0] / 784;                  // 65536

    float* TblG = nullptr;
    if (ws_size >= 1536 * sizeof(float)) {
        TblG = (float*)d_ws;
        build_tbl<<<6, 256, 0, stream>>>(W2, TblG);
    }

    int grid = (B + SPB - 1) / SPB;             // 512
    snn_if_kernel<<<grid, THREADS, 0, stream>>>(x, W1, b1, W2, b2, TblG, out, B);
}